// Round 13
// baseline (72.120 us; speedup 1.0000x reference)
//
#include <hip/hip_runtime.h>
#include <hip/hip_bf16.h>
#include <math.h>

#define NN 2048
#define LOG2E 1.4426950408889634f

typedef __attribute__((ext_vector_type(8))) short short8;
typedef __attribute__((ext_vector_type(4))) short s16x4;
typedef __attribute__((ext_vector_type(4))) float f32x4;

__device__ inline unsigned short f2bfu(float f) {
    __hip_bfloat16 h = __float2bfloat16(f);
    return *reinterpret_cast<const unsigned short*>(&h);
}
__device__ inline short f2bfs(float f) {
    __hip_bfloat16 h = __float2bfloat16(f);
    return *reinterpret_cast<const short*>(&h);
}
__device__ inline float bfu2f(unsigned short u) {
    return __uint_as_float(((unsigned int)u) << 16);
}

// ================= adjacency pack ==================================================
__device__ __forceinline__ void adj_task(
    const int* __restrict__ adj, unsigned long long* __restrict__ adjm, int task, int l)
{
    const int row = task >> 5, ch = task & 31;
    const int v = adj[(size_t)row * NN + ch * 64 + l];
    const unsigned long long bm = __ballot(v != 0);
    if (l == 0) adjm[task] = bm;
}

// ================= per-wave split-bf16 GEMM, packing fused in-register =============
// APACK=1: A from pre-packed split-bf16 frags (attn1's output).
// APACK=0: A from fp32 row-major (x), hi/lo split at compute time (same bytes).
// B always from fp32 row-major W (strided scalar loads + split at compute time).
// Epilogue: (1) bf16 PV B-frags direct from acc; (2) scores DIRECT-WRITTEN (no
// atomics): plane cb of sl/sr gets this block's exact 64-col partial (complete
// for L1 where dh=64; attn sums SRP planes for L2).
template<int APACK>
__device__ __forceinline__ void gemm_wave(
    const unsigned short* __restrict__ aHp, const unsigned short* __restrict__ aLp,
    const float* __restrict__ Afp,
    const float* __restrict__ Bfp, int BN,
    const float* __restrict__ av, unsigned short* __restrict__ gpO,
    float* __restrict__ slO, float* __restrict__ srO,
    int dh, int NT, int mt, int cb, int l)
{
    const int gq = l >> 4, n16 = l & 15;
    const int nt0 = cb * 4;
    const size_t abase = (size_t)mt * 16 * 512 + l * 8;   // APACK=1 frag base
    const int arow = mt * 16 + n16;                       // APACK=0 fp32 row
    const int bcol = nt0 * 16 + n16;

    f32x4 acc[4];
    #pragma unroll
    for (int nt = 0; nt < 4; ++nt) acc[nt] = f32x4{0.f, 0.f, 0.f, 0.f};

#define GLOAD(aH_, aL_, a0_, a1_, bf_, kt_) do {                                 \
    const int kk_ = (kt_);                                                       \
    if constexpr (APACK == 1) {                                                  \
        aH_ = *(const short8*)&aHp[abase + (size_t)kk_ * 512];                   \
        aL_ = *(const short8*)&aLp[abase + (size_t)kk_ * 512];                   \
    } else {                                                                     \
        a0_ = *(const f32x4*)&Afp[(size_t)arow * 512 + kk_ * 32 + 4 * gq];       \
        a1_ = *(const f32x4*)&Afp[(size_t)arow * 512 + kk_ * 32 + 4 * gq + 16];  \
    }                                                                            \
    _Pragma("unroll")                                                            \
    for (int nt_ = 0; nt_ < 4; ++nt_)                                            \
        _Pragma("unroll")                                                        \
        for (int e_ = 0; e_ < 8; ++e_)                                           \
            bf_[nt_][e_] = Bfp[(size_t)(kk_ * 32 + 4 * gq + (e_ & 3)             \
                               + 16 * (e_ >> 2)) * BN + bcol + nt_ * 16];        \
} while (0)

#define GCOMP(aH_, aL_, a0_, a1_, bf_) do {                                      \
    short8 aHr_, aLr_;                                                           \
    if constexpr (APACK == 1) { aHr_ = aH_; aLr_ = aL_; }                        \
    else {                                                                       \
        _Pragma("unroll")                                                        \
        for (int c_ = 0; c_ < 4; ++c_) {                                         \
            const unsigned short h0_ = f2bfu(a0_[c_]);                           \
            const unsigned short h1_ = f2bfu(a1_[c_]);                           \
            aHr_[c_] = (short)h0_;                                               \
            aHr_[c_ + 4] = (short)h1_;                                           \
            aLr_[c_] = f2bfs(a0_[c_] - bfu2f(h0_));                              \
            aLr_[c_ + 4] = f2bfs(a1_[c_] - bfu2f(h1_));                          \
        }                                                                        \
    }                                                                            \
    _Pragma("unroll")                                                            \
    for (int nt_ = 0; nt_ < 4; ++nt_) {                                          \
        short8 bH_, bL_;                                                         \
        _Pragma("unroll")                                                        \
        for (int e_ = 0; e_ < 8; ++e_) {                                         \
            const float v_ = bf_[nt_][e_];                                       \
            const unsigned short h_ = f2bfu(v_);                                 \
            bH_[e_] = (short)h_;                                                 \
            bL_[e_] = f2bfs(v_ - bfu2f(h_));                                     \
        }                                                                        \
        acc[nt_] = __builtin_amdgcn_mfma_f32_16x16x32_bf16(aHr_, bH_, acc[nt_], 0, 0, 0); \
        acc[nt_] = __builtin_amdgcn_mfma_f32_16x16x32_bf16(aHr_, bL_, acc[nt_], 0, 0, 0); \
        acc[nt_] = __builtin_amdgcn_mfma_f32_16x16x32_bf16(aLr_, bH_, acc[nt_], 0, 0, 0); \
    }                                                                            \
} while (0)

    short8 aHa, aLa, aHb, aLb;
    f32x4 a0a, a1a, a0b, a1b;
    float bfa[4][8], bfb[4][8];

    GLOAD(aHa, aLa, a0a, a1a, bfa, 0);
    GLOAD(aHb, aLb, a0b, a1b, bfb, 1);
    for (int kt = 0; kt < 16; kt += 2) {
        GCOMP(aHa, aLa, a0a, a1a, bfa);
        if (kt + 2 < 16) GLOAD(aHa, aLa, a0a, a1a, bfa, kt + 2);
        GCOMP(aHb, aLb, a0b, a1b, bfb);
        if (kt + 3 < 16) GLOAD(aHb, aLb, a0b, a1b, bfb, kt + 3);
    }
#undef GLOAD
#undef GCOMP

    // (1) bf16 PV fragments direct from acc
    #pragma unroll
    for (int nt = 0; nt < 4; ++nt) {
        s16x4 u;
        #pragma unroll
        for (int c = 0; c < 4; ++c) u[c] = (short)f2bfu(acc[nt][c]);
        const int f = (mt >> 1) * NT + (nt0 + nt);
        *(s16x4*)&gpO[(size_t)f * 512 + l * 8 + 4 * (mt & 1)] = u;
    }
    // (2) scores: 16-lane reduce, DIRECT write to plane cb (no atomics)
    const float* al = av;
    const float* ar = av + dh;
    float pl[4] = {0.f, 0.f, 0.f, 0.f}, pr[4] = {0.f, 0.f, 0.f, 0.f};
    #pragma unroll
    for (int nt = 0; nt < 4; ++nt) {
        const int q = (cb * 64 + 16 * nt + n16) & (dh - 1);
        const float wl = al[q], wr_ = ar[q];
        #pragma unroll
        for (int r = 0; r < 4; ++r) { pl[r] += acc[nt][r] * wl; pr[r] += acc[nt][r] * wr_; }
    }
    #pragma unroll
    for (int r = 0; r < 4; ++r) {
        #pragma unroll
        for (int off = 1; off < 16; off <<= 1) {
            pl[r] += __shfl_xor(pl[r], off);
            pr[r] += __shfl_xor(pr[r], off);
        }
    }
    if (n16 == 0) {
        #pragma unroll
        for (int r = 0; r < 4; ++r) {
            const int grow = 16 * mt + 4 * gq + r;
            slO[(size_t)cb * NN + grow] = pl[r] * LOG2E;
            srO[(size_t)cb * NN + grow] = pr[r] * LOG2E;
        }
    }
}

// ================= score-plane loaders (SRP=1: head-major; SRP=4: sum partials) ====
template<int SRP>
__device__ __forceinline__ float load_sl(const float* __restrict__ slv, int h, int row) {
    if constexpr (SRP == 1) {
        return slv[(size_t)h * NN + row];
    } else {
        float s = 0.f;
        #pragma unroll
        for (int p = 0; p < SRP; ++p) s += slv[(size_t)p * NN + row];
        return s;
    }
}
template<int SRP>
__device__ __forceinline__ f32x4 load_sr4(const float* __restrict__ srv, int h, int off) {
    f32x4 s = *(const f32x4*)&srv[(size_t)((SRP == 1) ? h : 0) * NN + off];
    if constexpr (SRP > 1) {
        #pragma unroll
        for (int p = 1; p < SRP; ++p) {
            const f32x4 t = *(const f32x4*)&srv[(size_t)p * NN + off];
            s += t;
        }
    }
    return s;
}

// ================= attention task (R8 structure + SRP score planes) ================
template<int MT, int OUTMODE, int SRP>
__device__ __forceinline__ void attn_task(
    const float* __restrict__ slv, const float* __restrict__ srv,
    const unsigned short* __restrict__ gp, const unsigned int* __restrict__ adjm32,
    float* __restrict__ out, unsigned short* __restrict__ aoH, unsigned short* __restrict__ aoL,
    int out_cols, int h, int do_elu, int ntg_total, int ib, int cb,
    float* accs_raw, float* zpf, int t)
{
    const int w = t >> 6, l = t & 63;
    const int gq = l >> 4, n16 = l & 15;
    const int i0 = ib * (MT * 16);
    const int ntg0 = cb * 4;
    int arow[MT];
    float slr[MT];
    #pragma unroll
    for (int mt = 0; mt < MT; ++mt) {
        arow[mt] = i0 + 16 * mt + n16;
        slr[mt] = load_sl<SRP>(slv, h, arow[mt]);
    }

    f32x4 acc[MT][4];
    float zacc[MT];
    #pragma unroll
    for (int mt = 0; mt < MT; ++mt) {
        zacc[mt] = 0.f;
        #pragma unroll
        for (int nt = 0; nt < 4; ++nt) acc[mt][nt] = f32x4{0.f, 0.f, 0.f, 0.f};
    }

#define LOADH(bf_, sr_, am_, tile_, s_) do {                                     \
    const int tl_ = (tile_);                                                     \
    _Pragma("unroll")                                                            \
    for (int nt_ = 0; nt_ < 4; ++nt_)                                            \
        bf_[nt_] = *(const short8*)&gp[                                          \
            (size_t)((2 * tl_ + (s_)) * ntg_total + ntg0 + nt_) * 512 + l * 8];  \
    _Pragma("unroll")                                                            \
    for (int hb_ = 0; hb_ < 2; ++hb_)                                            \
        sr_[hb_] = load_sr4<SRP>(srv, h, 64 * tl_ + 32 * (s_) + 16 * hb_ + 4 * gq); \
    _Pragma("unroll")                                                            \
    for (int mt_ = 0; mt_ < MT; ++mt_)                                           \
        am_[mt_] = adjm32[((size_t)arow[mt_] * 32 + tl_) * 2 + (s_)];            \
} while (0)

#define COMPH(bf_, sr_, am_) do {                                                \
    short8 af_[MT];                                                              \
    _Pragma("unroll")                                                            \
    for (int mt_ = 0; mt_ < MT; ++mt_) {                                         \
        const unsigned am32_ = am_[mt_] >> (4 * gq);                             \
        _Pragma("unroll")                                                        \
        for (int hb_ = 0; hb_ < 2; ++hb_) {                                      \
            const f32x4 s4_ = sr_[hb_];                                          \
            _Pragma("unroll")                                                    \
            for (int c_ = 0; c_ < 4; ++c_) {                                     \
                float f_ = slr[mt_] + s4_[c_];                                   \
                f_ = fmaxf(f_, 0.2f * f_);                                       \
                float wv_ = __builtin_amdgcn_exp2f(f_);                          \
                const int msk_ = (int)(am32_ << (31 - (c_ + 16 * hb_))) >> 31;   \
                wv_ = __int_as_float(__float_as_int(wv_) & msk_);                \
                zacc[mt_] += wv_;                                                \
                af_[mt_][4 * hb_ + c_] = f2bfs(wv_);                             \
            }                                                                    \
        }                                                                        \
    }                                                                            \
    _Pragma("unroll")                                                            \
    for (int mt_ = 0; mt_ < MT; ++mt_)                                           \
        _Pragma("unroll")                                                        \
        for (int nt_ = 0; nt_ < 4; ++nt_)                                        \
            acc[mt_][nt_] = __builtin_amdgcn_mfma_f32_16x16x32_bf16(             \
                af_[mt_], bf_[nt_], acc[mt_][nt_], 0, 0, 0);                     \
} while (0)

    unsigned amA[MT], amB[MT];
    f32x4 srA[2], srB[2];
    short8 bfA[4], bfB[4];

    LOADH(bfA, srA, amA, w, 0);
    LOADH(bfB, srB, amB, w, 1);
    #pragma unroll
    for (int k = 0; k < 4; ++k) {
        const int tn = (k < 3) ? (w + 8 * (k + 1)) : (w + 8 * k);   // guarded prefetch
        COMPH(bfA, srA, amA);
        LOADH(bfA, srA, amA, tn, 0);
        COMPH(bfB, srB, amB);
        LOADH(bfB, srB, amB, tn, 1);
    }
#undef LOADH
#undef COMPH

    #pragma unroll
    for (int mt = 0; mt < MT; ++mt) {
        zacc[mt] += __shfl_xor(zacc[mt], 16);
        zacc[mt] += __shfl_xor(zacc[mt], 32);
    }
    if (l < 16) {
        #pragma unroll
        for (int mt = 0; mt < MT; ++mt) zpf[w * (MT * 16) + 16 * mt + l] = zacc[mt];
    }

    if constexpr (OUTMODE == 0) {
        #pragma unroll
        for (int nt = 0; nt < 4; ++nt)
            #pragma unroll
            for (int r = 0; r < 4; ++r)
                accs_raw[((w * 4 + nt) * 4 + r) * 65 + l] = acc[0][nt][r];
        __syncthreads();
        #pragma unroll
        for (int idx = 0; idx < 2; ++idx) {
            const int flat = w + 8 * idx;            // 0..15
            const int nt = flat >> 2, r = flat & 3;
            const int ro = 4 * gq + r;
            float z = 0.f, v = 0.f;
            #pragma unroll
            for (int jj = 0; jj < 8; ++jj) {
                z += zpf[jj * 16 + ro];
                v += accs_raw[((jj * 4 + nt) * 4 + r) * 65 + l];
            }
            float o = v / z;
            if (do_elu) o = (o > 0.f) ? o : (__builtin_amdgcn_exp2f(o * LOG2E) - 1.f);
            out[(size_t)(i0 + ro) * out_cols + cb * 64 + nt * 16 + n16] = o;
        }
    } else {
        const int mtl = w & 1, eh = (w >> 1) & 1;
        const int rowl = l & 15, colq = l >> 4;
        #pragma unroll
        for (int h2 = 0; h2 < 2; ++h2) {
            #pragma unroll
            for (int mt = 0; mt < MT; ++mt)
                #pragma unroll
                for (int ntl = 0; ntl < 2; ++ntl)
                    #pragma unroll
                    for (int r = 0; r < 4; ++r)
                        accs_raw[(((w * 2 + mt) * 2 + ntl) * 4 + r) * 65 + l] =
                            acc[mt][2 * h2 + ntl][r];
            __syncthreads();
            if (w < 4) {
                const int grow = 16 * mtl + rowl;
                float z = 0.f;
                #pragma unroll
                for (int jj = 0; jj < 8; ++jj) z += zpf[jj * 32 + grow];
                const float rz = 1.0f / z;
                unsigned short uh[4], ul[4];
                #pragma unroll
                for (int c = 0; c < 4; ++c) {
                    const int c16 = 4 * colq + c;
                    float v = 0.f;
                    #pragma unroll
                    for (int jj = 0; jj < 8; ++jj)
                        v += accs_raw[(((jj * 2 + mtl) * 2 + eh) * 4 + (rowl & 3)) * 65
                                      + (rowl >> 2) * 16 + c16];
                    float o = v * rz;
                    o = (o > 0.f) ? o : (__builtin_amdgcn_exp2f(o * LOG2E) - 1.f);  // ELU
                    const unsigned short hi = f2bfu(o);
                    uh[c] = hi;
                    ul[c] = f2bfu(o - bfu2f(hi));
                }
                const int mtg = ib * 2 + mtl;
                const int kt = 2 * cb + h2;
                const size_t off = ((size_t)mtg * 16 + kt) * 512 + l * 8 + 4 * eh;
                *(s16x4*)&aoH[off] = *(const s16x4*)uh;
                *(s16x4*)&aoL[off] = *(const s16x4*)ul;
            }
            __syncthreads();
        }
    }
}

// ================= kernels =========================================================
// gemm: 2D grid (ngx + nadjx, ncb). blockIdx.x < ngx -> GEMM (mt = x*4+w, cb = y);
// else -> adjacency-pack block (concurrent, pure memory work).
template<int APACK>
__global__ __launch_bounds__(256, 2) void gemm_k(
    const unsigned short* __restrict__ aHp, const unsigned short* __restrict__ aLp,
    const float* __restrict__ Afp, const float* __restrict__ Bfp, int BN,
    const float* __restrict__ av, unsigned short* __restrict__ gpO,
    float* __restrict__ slO, float* __restrict__ srO,
    int dh, int NT, int ngx,
    const int* __restrict__ adj, unsigned long long* __restrict__ adjm)
{
    const int t = threadIdx.x, w = t >> 6, l = t & 63;
    const int bx = blockIdx.x, by = blockIdx.y;
    if (bx < ngx) {
        gemm_wave<APACK>(aHp, aLp, Afp, Bfp, BN, av, gpO, slO, srO,
                         dh, NT, bx * 4 + w, by, l);
    } else {
        const int gwave = ((bx - ngx) * 8 + by) * 4 + w;    // 0..4095
        #pragma unroll 4
        for (int i = 0; i < 16; ++i)
            adj_task(adj, adjm, gwave + 4096 * i, l);
    }
}

// attn: 2D grid (R8 shape): ib = blockIdx.x, cb = blockIdx.y.
template<int MT, int OUTMODE, int SRP>
__global__ __launch_bounds__(512, 4) void attn_k(
    const float* __restrict__ slv, const float* __restrict__ srv,
    const unsigned short* __restrict__ gp, const unsigned int* __restrict__ adjm32,
    float* __restrict__ out, unsigned short* __restrict__ aoH, unsigned short* __restrict__ aoL,
    int out_cols, int hsel, int do_elu, int ntg_total)
{
    __shared__ float accs_raw[8320];
    __shared__ float zpf[256];
    const int ib = blockIdx.x, cb = blockIdx.y;
    const int h = (hsel < 0) ? cb : hsel;
    attn_task<MT, OUTMODE, SRP>(slv, srv, gp, adjm32, out, aoH, aoL, out_cols, h, do_elu,
                                ntg_total, ib, cb, accs_raw, zpf, threadIdx.x);
}

extern "C" void kernel_launch(void* const* d_in, const int* in_sizes, int n_in,
                              void* d_out, int out_size, void* d_ws, size_t ws_size,
                              hipStream_t stream)
{
    const float* x   = (const float*)d_in[0];   // 2048 x 512
    const int*   adj = (const int*)  d_in[1];   // 2048 x 2048
    const float* W1  = (const float*)d_in[2];   // 512 x 512
    const float* a1  = (const float*)d_in[3];   // 128
    const float* W2  = (const float*)d_in[4];   // 512 x 256
    const float* a2  = (const float*)d_in[5];   // 512
    float* outp = (float*)d_out;                // 2048 x 256

    float* sl1  = (float*)d_ws;                 // 8 planes x 2048 (complete, head-major)
    float* sr1  = sl1 + 8 * 2048;
    float* sl2p = sr1 + 8 * 2048;               // 4 partial planes x 2048
    float* sr2p = sl2p + 4 * 2048;
    unsigned long long* adjm = (unsigned long long*)(sr2p + 4 * 2048);  // 65536 u64
    unsigned short* gp1 = (unsigned short*)(adjm + 65536);              // 2048 frags
    unsigned short* gp2 = gp1 + 2048 * 512;     // 1024 frags
    unsigned short* ahH = gp2 + 1024 * 512;     // 2048 frags (attn1's emitted A)
    unsigned short* ahL = ahH + 2048 * 512;

    // D1: L1 GEMM (in-reg pack of x and W1, direct scores) + 1024 adj-pack blocks
    gemm_k<0><<<dim3(160, 8), 256, 0, stream>>>(
        nullptr, nullptr, x, W1, 512, a1, gp1, sl1, sr1, 64, 32, 32, adj, adjm);

    // D2: L1 attention (MT=2, emits split-bf16 A-frags, ELU); scores complete (SRP=1)
    attn_k<2, 1, 1><<<dim3(64, 8), 512, 0, stream>>>(
        sl1, sr1, gp1, (const unsigned int*)adjm, nullptr, ahH, ahL, 512, -1, 1, 32);

    // D3: L2 GEMM (A pre-packed, W2 in-reg pack, partial scores to 4 planes)
    gemm_k<1><<<dim3(32, 4), 256, 0, stream>>>(
        ahH, ahL, nullptr, W2, 256, a2, gp2, sl2p, sr2p, 256, 16, 32, nullptr, nullptr);

    // D4: L2 attention (MT=1, fp32 out; sums 4 score planes, SRP=4)
    attn_k<1, 0, 4><<<dim3(128, 4), 512, 0, stream>>>(
        sl2p, sr2p, gp2, (const unsigned int*)adjm, outp, nullptr, nullptr, 256, 0, 0, 16);
}

// Round 14
// 56.164 us; speedup vs baseline: 1.2841x; 1.2841x over previous
//
#include <hip/hip_runtime.h>
#include <hip/hip_bf16.h>
#include <math.h>

#define NN 2048
#define LOG2E 1.4426950408889634f

typedef __attribute__((ext_vector_type(8))) short short8;
typedef __attribute__((ext_vector_type(4))) short s16x4;
typedef __attribute__((ext_vector_type(4))) float f32x4;

__device__ inline unsigned short f2bfu(float f) {
    __hip_bfloat16 h = __float2bfloat16(f);
    return *reinterpret_cast<const unsigned short*>(&h);
}
__device__ inline short f2bfs(float f) {
    __hip_bfloat16 h = __float2bfloat16(f);
    return *reinterpret_cast<const short*>(&h);
}
__device__ inline float bfu2f(unsigned short u) {
    return __uint_as_float(((unsigned int)u) << 16);
}

// ---------------- fused prep: adj masks + score-zero + W packs + x A-frags --------
__global__ __launch_bounds__(256) void prep(
    const int* __restrict__ adj, unsigned long long* __restrict__ adjm,
    float* __restrict__ zeros,
    const float* __restrict__ W1, unsigned short* __restrict__ w1H, unsigned short* __restrict__ w1L,
    const float* __restrict__ W2, unsigned short* __restrict__ w2H, unsigned short* __restrict__ w2L,
    const float* __restrict__ x, unsigned short* __restrict__ axH, unsigned short* __restrict__ axL)
{
    const int b = blockIdx.x, t = threadIdx.x, w = t >> 6, l = t & 63;
    const int gq = l >> 4, n16 = l & 15;
    // --- adjacency -> per-row 64-bit masks (all 16384 blocks) ---
    {
        const int gw = b * 4 + w;
        const int row = gw >> 5, ch = gw & 31;
        const int v = adj[(size_t)row * NN + ch * 64 + l];
        const unsigned long long bm = __ballot(v != 0);
        if (l == 0) adjm[gw] = bm;
    }
    if (b < 144) {
        zeros[b * 256 + t] = 0.f;           // sl1,sr1,sl2,sr2 (36864 floats)
    } else if (b >= 256 && b < 448) {
        // --- W1/W2 -> split-bf16 B-frags ---
        int f = (b - 256) * 4 + w;          // 0..767
        const float* B; unsigned short *bH, *bL; int N;
        if (f < 512) { B = W1; bH = w1H; bL = w1L; N = 512; }
        else         { B = W2; bH = w2H; bL = w2L; N = 256; f -= 512; }
        const int nt = f >> 4, kt = f & 15;
        const int col = nt * 16 + n16;
        unsigned short uh[8], ul[8];
        #pragma unroll
        for (int e = 0; e < 8; ++e) {
            const int k = kt * 32 + 4 * gq + (e & 3) + 16 * (e >> 2);
            const float v = B[(size_t)k * N + col];
            const unsigned short hi = f2bfu(v);
            uh[e] = hi;
            ul[e] = f2bfu(v - bfu2f(hi));
        }
        *(short8*)&bH[(size_t)f * 512 + l * 8] = *(const short8*)uh;
        *(short8*)&bL[(size_t)f * 512 + l * 8] = *(const short8*)ul;
    } else if (b >= 448 && b < 960) {
        // --- x -> split-bf16 A-frags (K=512, KT=16) ---
        const int f = (b - 448) * 4 + w;    // 0..2047
        const int mt = f >> 4, kt = f & 15;
        const int row = mt * 16 + n16;
        const int k0 = kt * 32 + 4 * gq;
        unsigned short uh[8], ul[8];
        #pragma unroll
        for (int eh = 0; eh < 2; ++eh) {
            const float4 v4 = *(const float4*)&x[(size_t)row * 512 + k0 + 16 * eh];
            const float vv[4] = {v4.x, v4.y, v4.z, v4.w};
            #pragma unroll
            for (int c = 0; c < 4; ++c) {
                const float v = vv[c];
                const unsigned short hi = f2bfu(v);
                uh[4 * eh + c] = hi;
                ul[4 * eh + c] = f2bfu(v - bfu2f(hi));
            }
        }
        *(short8*)&axH[(size_t)f * 512 + l * 8] = *(const short8*)uh;
        *(short8*)&axL[(size_t)f * 512 + l * 8] = *(const short8*)ul;
    }
}

// ---------------- split-bf16 MFMA GEMM, fused epilogue -----------------------------
__global__ __launch_bounds__(256, 2) void gemm_fused(
    const unsigned short* __restrict__ aH, const unsigned short* __restrict__ aL,
    const unsigned short* __restrict__ bH, const unsigned short* __restrict__ bL,
    const float* __restrict__ av, unsigned short* __restrict__ gpO,
    float* __restrict__ slO, float* __restrict__ srO,
    int KT, int dh, int NT)
{
    const int t = threadIdx.x, w = t >> 6, l = t & 63;
    const int gq = l >> 4, n16 = l & 15;
    const int mt = blockIdx.x * 4 + w;
    const int cb = blockIdx.y;
    const int nt0 = cb * 4;
    const size_t abase = (size_t)mt * KT * 512 + l * 8;

    f32x4 acc[4];
    #pragma unroll
    for (int nt = 0; nt < 4; ++nt) acc[nt] = f32x4{0.f, 0.f, 0.f, 0.f};

#define GL(aH_v, aL_v, bH_v, bL_v, kt_) do {                                     \
    const int kk_ = (kt_);                                                       \
    aH_v = *(const short8*)&aH[abase + (size_t)kk_ * 512];                       \
    aL_v = *(const short8*)&aL[abase + (size_t)kk_ * 512];                       \
    _Pragma("unroll")                                                            \
    for (int nt_ = 0; nt_ < 4; ++nt_) {                                          \
        const size_t bo_ = ((size_t)(nt0 + nt_) * KT + kk_) * 512 + l * 8;       \
        bH_v[nt_] = *(const short8*)&bH[bo_];                                    \
        bL_v[nt_] = *(const short8*)&bL[bo_];                                    \
    }                                                                            \
} while (0)

#define GC(aH_v, aL_v, bH_v, bL_v) do {                                          \
    _Pragma("unroll")                                                            \
    for (int nt_ = 0; nt_ < 4; ++nt_) {                                          \
        acc[nt_] = __builtin_amdgcn_mfma_f32_16x16x32_bf16(aH_v, bH_v[nt_], acc[nt_], 0, 0, 0); \
        acc[nt_] = __builtin_amdgcn_mfma_f32_16x16x32_bf16(aH_v, bL_v[nt_], acc[nt_], 0, 0, 0); \
        acc[nt_] = __builtin_amdgcn_mfma_f32_16x16x32_bf16(aL_v, bH_v[nt_], acc[nt_], 0, 0, 0); \
    }                                                                            \
} while (0)

    short8 aHa, aLa, bHa[4], bLa[4], aHb, aLb, bHb[4], bLb[4];
    GL(aHa, aLa, bHa, bLa, 0);
    GL(aHb, aLb, bHb, bLb, 1);
    for (int kt = 0; kt < KT; kt += 2) {
        GC(aHa, aLa, bHa, bLa);
        if (kt + 2 < KT) GL(aHa, aLa, bHa, bLa, kt + 2);
        GC(aHb, aLb, bHb, bLb);
        if (kt + 3 < KT) GL(aHb, aLb, bHb, bLb, kt + 3);
    }
#undef GL
#undef GC

    // (1) bf16 PV fragments direct from acc
    #pragma unroll
    for (int nt = 0; nt < 4; ++nt) {
        s16x4 u;
        #pragma unroll
        for (int c = 0; c < 4; ++c) u[c] = (short)f2bfu(acc[nt][c]);
        const int f = (mt >> 1) * NT + (nt0 + nt);
        *(s16x4*)&gpO[(size_t)f * 512 + l * 8 + 4 * (mt & 1)] = u;
    }
    // (2) scores via 16-lane reduce + atomicAdd
    const float* al = av;
    const float* ar = av + dh;
    float pl[4] = {0.f, 0.f, 0.f, 0.f}, pr[4] = {0.f, 0.f, 0.f, 0.f};
    #pragma unroll
    for (int nt = 0; nt < 4; ++nt) {
        const int q = (cb * 64 + 16 * nt + n16) & (dh - 1);
        const float wl = al[q], wr_ = ar[q];
        #pragma unroll
        for (int r = 0; r < 4; ++r) { pl[r] += acc[nt][r] * wl; pr[r] += acc[nt][r] * wr_; }
    }
    #pragma unroll
    for (int r = 0; r < 4; ++r) {
        #pragma unroll
        for (int off = 1; off < 16; off <<= 1) {
            pl[r] += __shfl_xor(pl[r], off);
            pr[r] += __shfl_xor(pr[r], off);
        }
    }
    if (n16 == 0) {
        const int hbase = (dh == 64 ? cb : 0) * NN;
        #pragma unroll
        for (int r = 0; r < 4; ++r) {
            const int grow = 16 * mt + 4 * gq + r;
            atomicAdd(&slO[hbase + grow], pl[r] * LOG2E);
            atomicAdd(&srO[hbase + grow], pr[r] * LOG2E);
        }
    }
}

// ---------------- fused masked-softmax attention, MT row-tiles/wave ----------------
// All 8 waves cover the same MT*16 rows; js = w (8-way j-split), NITER = 4 tiles.
// Half-tile ping-pong: buffer = {4 B-frags, 2 sr-vec4, MT u32 masks} per 32-j half.
template<int MT, int OUTMODE>
__global__ __launch_bounds__(512, 4) void attn_mfma6(
    const float* __restrict__ slv, const float* __restrict__ srv,
    const unsigned short* __restrict__ gp, const unsigned int* __restrict__ adjm32,
    float* __restrict__ out, unsigned short* __restrict__ aoH, unsigned short* __restrict__ aoL,
    int out_cols, int hsel, int do_elu, int ntg_total)
{
    const int t = threadIdx.x, w = t >> 6, l = t & 63;
    const int gq = l >> 4, n16 = l & 15;
    const int i0 = blockIdx.x * (MT * 16);
    const int cb = blockIdx.y;
    const int h = (hsel < 0) ? cb : hsel;
    const int ntg0 = cb * 4;
    const float* srh = srv + (size_t)h * NN;
    int arow[MT];
    float slr[MT];
    #pragma unroll
    for (int mt = 0; mt < MT; ++mt) {
        arow[mt] = i0 + 16 * mt + n16;
        slr[mt] = slv[(size_t)h * NN + arow[mt]];
    }

    __shared__ float accs_raw[8320];   // 33280 B, 65-padded rows
    __shared__ float zp[8][MT * 16];

    f32x4 acc[MT][4];
    float zacc[MT];
    #pragma unroll
    for (int mt = 0; mt < MT; ++mt) {
        zacc[mt] = 0.f;
        #pragma unroll
        for (int nt = 0; nt < 4; ++nt) acc[mt][nt] = f32x4{0.f, 0.f, 0.f, 0.f};
    }

#define LOADH(bf_, sr_, am_, tile_, s_) do {                                     \
    const int tl_ = (tile_);                                                     \
    _Pragma("unroll")                                                            \
    for (int nt_ = 0; nt_ < 4; ++nt_)                                            \
        bf_[nt_] = *(const short8*)&gp[                                          \
            (size_t)((2 * tl_ + (s_)) * ntg_total + ntg0 + nt_) * 512 + l * 8];  \
    _Pragma("unroll")                                                            \
    for (int hb_ = 0; hb_ < 2; ++hb_)                                            \
        sr_[hb_] = *(const f32x4*)&srh[64 * tl_ + 32 * (s_) + 16 * hb_ + 4 * gq];\
    _Pragma("unroll")                                                            \
    for (int mt_ = 0; mt_ < MT; ++mt_)                                           \
        am_[mt_] = adjm32[((size_t)arow[mt_] * 32 + tl_) * 2 + (s_)];            \
} while (0)

#define COMPH(bf_, sr_, am_) do {                                                \
    short8 af_[MT];                                                              \
    _Pragma("unroll")                                                            \
    for (int mt_ = 0; mt_ < MT; ++mt_) {                                         \
        const unsigned am32_ = am_[mt_] >> (4 * gq);                             \
        _Pragma("unroll")                                                        \
        for (int hb_ = 0; hb_ < 2; ++hb_) {                                      \
            const f32x4 s4_ = sr_[hb_];                                          \
            _Pragma("unroll")                                                    \
            for (int c_ = 0; c_ < 4; ++c_) {                                     \
                float f_ = slr[mt_] + s4_[c_];                                   \
                f_ = fmaxf(f_, 0.2f * f_);                                       \
                float wv_ = __builtin_amdgcn_exp2f(f_);                          \
                const int msk_ = (int)(am32_ << (31 - (c_ + 16 * hb_))) >> 31;   \
                wv_ = __int_as_float(__float_as_int(wv_) & msk_);                \
                zacc[mt_] += wv_;                                                \
                af_[mt_][4 * hb_ + c_] = f2bfs(wv_);                             \
            }                                                                    \
        }                                                                        \
    }                                                                            \
    _Pragma("unroll")                                                            \
    for (int mt_ = 0; mt_ < MT; ++mt_)                                           \
        _Pragma("unroll")                                                        \
        for (int nt_ = 0; nt_ < 4; ++nt_)                                        \
            acc[mt_][nt_] = __builtin_amdgcn_mfma_f32_16x16x32_bf16(             \
                af_[mt_], bf_[nt_], acc[mt_][nt_], 0, 0, 0);                     \
} while (0)

    unsigned amA[MT], amB[MT];
    f32x4 srA[2], srB[2];
    short8 bfA[4], bfB[4];

    LOADH(bfA, srA, amA, w, 0);
    LOADH(bfB, srB, amB, w, 1);
    #pragma unroll
    for (int k = 0; k < 4; ++k) {
        const int tn = (k < 3) ? (w + 8 * (k + 1)) : (w + 8 * k);   // guarded prefetch
        COMPH(bfA, srA, amA);
        LOADH(bfA, srA, amA, tn, 0);
        COMPH(bfB, srB, amB);
        LOADH(bfB, srB, amB, tn, 1);
    }
#undef LOADH
#undef COMPH

    // ---- Z reduce: lanes {l, l^16, l^32, l^48} share a row ----
    #pragma unroll
    for (int mt = 0; mt < MT; ++mt) {
        zacc[mt] += __shfl_xor(zacc[mt], 16);
        zacc[mt] += __shfl_xor(zacc[mt], 32);
    }
    if (l < 16) {
        #pragma unroll
        for (int mt = 0; mt < MT; ++mt) zp[w][16 * mt + l] = zacc[mt];
    }

    if constexpr (OUTMODE == 0) {
        // MT == 1: single round, fp32 out
        #pragma unroll
        for (int nt = 0; nt < 4; ++nt)
            #pragma unroll
            for (int r = 0; r < 4; ++r)
                accs_raw[((w * 4 + nt) * 4 + r) * 65 + l] = acc[0][nt][r];
        __syncthreads();
        #pragma unroll
        for (int idx = 0; idx < 2; ++idx) {
            const int flat = w + 8 * idx;            // 0..15
            const int nt = flat >> 2, r = flat & 3;
            const int ro = 4 * gq + r;
            float z = 0.f, v = 0.f;
            #pragma unroll
            for (int jj = 0; jj < 8; ++jj) {
                z += zp[jj][ro];
                v += accs_raw[((jj * 4 + nt) * 4 + r) * 65 + l];
            }
            float o = v / z;
            if (do_elu) o = (o > 0.f) ? o : (__builtin_amdgcn_exp2f(o * LOG2E) - 1.f);
            out[(size_t)(i0 + ro) * out_cols + cb * 64 + nt * 16 + n16] = o;
        }
    } else {
        // MT == 2: two rounds (one per ktl); emit split-bf16 A-frags (ELU applied)
        const int mtl = w & 1, eh = (w >> 1) & 1;
        const int rowl = l & 15, colq = l >> 4;
        #pragma unroll
        for (int h2 = 0; h2 < 2; ++h2) {
            #pragma unroll
            for (int mt = 0; mt < MT; ++mt)
                #pragma unroll
                for (int ntl = 0; ntl < 2; ++ntl)
                    #pragma unroll
                    for (int r = 0; r < 4; ++r)
                        accs_raw[(((w * 2 + mt) * 2 + ntl) * 4 + r) * 65 + l] =
                            acc[mt][2 * h2 + ntl][r];
            __syncthreads();
            if (w < 4) {
                const int grow = 16 * mtl + rowl;
                float z = 0.f;
                #pragma unroll
                for (int jj = 0; jj < 8; ++jj) z += zp[jj][grow];
                const float rz = 1.0f / z;
                unsigned short uh[4], ul[4];
                #pragma unroll
                for (int c = 0; c < 4; ++c) {
                    const int c16 = 4 * colq + c;
                    float v = 0.f;
                    #pragma unroll
                    for (int jj = 0; jj < 8; ++jj)
                        v += accs_raw[(((jj * 2 + mtl) * 2 + eh) * 4 + (rowl & 3)) * 65
                                      + (rowl >> 2) * 16 + c16];
                    float o = v * rz;
                    o = (o > 0.f) ? o : (__builtin_amdgcn_exp2f(o * LOG2E) - 1.f);  // ELU
                    const unsigned short hi = f2bfu(o);
                    uh[c] = hi;
                    ul[c] = f2bfu(o - bfu2f(hi));
                }
                const int mtg = blockIdx.x * 2 + mtl;
                const int kt = 2 * cb + h2;
                const size_t off = ((size_t)mtg * 16 + kt) * 512 + l * 8 + 4 * eh;
                *(s16x4*)&aoH[off] = *(const s16x4*)uh;
                *(s16x4*)&aoL[off] = *(const s16x4*)ul;
            }
            __syncthreads();
        }
    }
}

extern "C" void kernel_launch(void* const* d_in, const int* in_sizes, int n_in,
                              void* d_out, int out_size, void* d_ws, size_t ws_size,
                              hipStream_t stream)
{
    const float* x   = (const float*)d_in[0];   // 2048 x 512
    const int*   adj = (const int*)  d_in[1];   // 2048 x 2048
    const float* W1  = (const float*)d_in[2];   // 512 x 512
    const float* a1  = (const float*)d_in[3];   // 128
    const float* W2  = (const float*)d_in[4];   // 512 x 256
    const float* a2  = (const float*)d_in[5];   // 512
    float* out = (float*)d_out;                 // 2048 x 256

    // ---- workspace layout (scores first: zeroed by prep, 36864 floats) ----
    float* sl1 = (float*)d_ws;                  // 8*2048
    float* sr1 = sl1 + 8 * 2048;
    float* sl2 = sr1 + 8 * 2048;                // 2048
    float* sr2 = sl2 + 2048;
    unsigned long long* adjm = (unsigned long long*)(sr2 + 2048);   // 65536 u64
    unsigned short* gp1 = (unsigned short*)(adjm + 65536);          // 2048 frags * 512
    unsigned short* gp2 = gp1 + 2048 * 512;     // 1024 frags
    unsigned short* axH = gp2 + 1024 * 512;     // x A-frags: 2048 frags
    unsigned short* axL = axH + 2048 * 512;
    unsigned short* ahH = axL + 2048 * 512;     // hb A-frags: 2048 frags
    unsigned short* ahL = ahH + 2048 * 512;
    unsigned short* w1H = ahL + 2048 * 512;     // W1 B-frags: 512 frags
    unsigned short* w1L = w1H + 512 * 512;
    unsigned short* w2H = w1L + 512 * 512;      // W2 B-frags: 256 frags
    unsigned short* w2L = w2H + 256 * 512;

    prep<<<dim3(16384), 256, 0, stream>>>(adj, adjm, sl1,
                                          W1, w1H, w1L, W2, w2H, w2L, x, axH, axL);

    // ---- layer 1 ----
    gemm_fused<<<dim3(32, 8), 256, 0, stream>>>(axH, axL, w1H, w1L, a1, gp1, sl1, sr1, 16, 64, 32);
    attn_mfma6<2, 1><<<dim3(64, 8), 512, 0, stream>>>(sl1, sr1, gp1, (const unsigned int*)adjm,
                                                      nullptr, ahH, ahL, 512, -1, 1, 32);

    // ---- layer 2 ----
    gemm_fused<<<dim3(32, 4), 256, 0, stream>>>(ahH, ahL, w2H, w2L, a2, gp2, sl2, sr2, 16, 256, 16);
    attn_mfma6<1, 0><<<dim3(128, 4), 512, 0, stream>>>(sl2, sr2, gp2, (const unsigned int*)adjm,
                                                       out, nullptr, nullptr, 256, 0, 0, 16);
}

// Round 15
// 54.860 us; speedup vs baseline: 1.3146x; 1.0238x over previous
//
#include <hip/hip_runtime.h>
#include <hip/hip_bf16.h>
#include <math.h>

#define NN 2048
#define LOG2E 1.4426950408889634f

typedef __attribute__((ext_vector_type(8))) short short8;
typedef __attribute__((ext_vector_type(4))) short s16x4;
typedef __attribute__((ext_vector_type(4))) float f32x4;

__device__ inline unsigned short f2bfu(float f) {
    __hip_bfloat16 h = __float2bfloat16(f);
    return *reinterpret_cast<const unsigned short*>(&h);
}
__device__ inline short f2bfs(float f) {
    __hip_bfloat16 h = __float2bfloat16(f);
    return *reinterpret_cast<const short*>(&h);
}
__device__ inline float bfu2f(unsigned short u) {
    return __uint_as_float(((unsigned int)u) << 16);
}

// ---------------- fused prep: adj masks + score-zero + W packs + x A-frags --------
__global__ __launch_bounds__(256) void prep(
    const int* __restrict__ adj, unsigned long long* __restrict__ adjm,
    float* __restrict__ zeros,
    const float* __restrict__ W1, unsigned short* __restrict__ w1H, unsigned short* __restrict__ w1L,
    const float* __restrict__ W2, unsigned short* __restrict__ w2H, unsigned short* __restrict__ w2L,
    const float* __restrict__ x, unsigned short* __restrict__ axH, unsigned short* __restrict__ axL)
{
    const int b = blockIdx.x, t = threadIdx.x, w = t >> 6, l = t & 63;
    const int gq = l >> 4, n16 = l & 15;
    // --- adjacency -> per-row 64-bit masks (all 16384 blocks) ---
    {
        const int gw = b * 4 + w;
        const int row = gw >> 5, ch = gw & 31;
        const int v = adj[(size_t)row * NN + ch * 64 + l];
        const unsigned long long bm = __ballot(v != 0);
        if (l == 0) adjm[gw] = bm;
    }
    if (b < 144) {
        zeros[b * 256 + t] = 0.f;           // sl1,sr1,sl2,sr2 (36864 floats)
    } else if (b >= 256 && b < 448) {
        // --- W1/W2 -> split-bf16 B-frags ---
        int f = (b - 256) * 4 + w;          // 0..767
        const float* B; unsigned short *bH, *bL; int N;
        if (f < 512) { B = W1; bH = w1H; bL = w1L; N = 512; }
        else         { B = W2; bH = w2H; bL = w2L; N = 256; f -= 512; }
        const int nt = f >> 4, kt = f & 15;
        const int col = nt * 16 + n16;
        unsigned short uh[8], ul[8];
        #pragma unroll
        for (int e = 0; e < 8; ++e) {
            const int k = kt * 32 + 4 * gq + (e & 3) + 16 * (e >> 2);
            const float v = B[(size_t)k * N + col];
            const unsigned short hi = f2bfu(v);
            uh[e] = hi;
            ul[e] = f2bfu(v - bfu2f(hi));
        }
        *(short8*)&bH[(size_t)f * 512 + l * 8] = *(const short8*)uh;
        *(short8*)&bL[(size_t)f * 512 + l * 8] = *(const short8*)ul;
    } else if (b >= 448 && b < 960) {
        // --- x -> split-bf16 A-frags (K=512, KT=16) ---
        const int f = (b - 448) * 4 + w;    // 0..2047
        const int mt = f >> 4, kt = f & 15;
        const int row = mt * 16 + n16;
        const int k0 = kt * 32 + 4 * gq;
        unsigned short uh[8], ul[8];
        #pragma unroll
        for (int eh = 0; eh < 2; ++eh) {
            const float4 v4 = *(const float4*)&x[(size_t)row * 512 + k0 + 16 * eh];
            const float vv[4] = {v4.x, v4.y, v4.z, v4.w};
            #pragma unroll
            for (int c = 0; c < 4; ++c) {
                const float v = vv[c];
                const unsigned short hi = f2bfu(v);
                uh[4 * eh + c] = hi;
                ul[4 * eh + c] = f2bfu(v - bfu2f(hi));
            }
        }
        *(short8*)&axH[(size_t)f * 512 + l * 8] = *(const short8*)uh;
        *(short8*)&axL[(size_t)f * 512 + l * 8] = *(const short8*)ul;
    }
}

// ---------------- split-bf16 MFMA GEMM, fused epilogue -----------------------------
__global__ __launch_bounds__(256, 2) void gemm_fused(
    const unsigned short* __restrict__ aH, const unsigned short* __restrict__ aL,
    const unsigned short* __restrict__ bH, const unsigned short* __restrict__ bL,
    const float* __restrict__ av, unsigned short* __restrict__ gpO,
    float* __restrict__ slO, float* __restrict__ srO,
    int KT, int dh, int NT)
{
    const int t = threadIdx.x, w = t >> 6, l = t & 63;
    const int gq = l >> 4, n16 = l & 15;
    const int mt = blockIdx.x * 4 + w;
    const int cb = blockIdx.y;
    const int nt0 = cb * 4;
    const size_t abase = (size_t)mt * KT * 512 + l * 8;

    f32x4 acc[4];
    #pragma unroll
    for (int nt = 0; nt < 4; ++nt) acc[nt] = f32x4{0.f, 0.f, 0.f, 0.f};

#define GL(aH_v, aL_v, bH_v, bL_v, kt_) do {                                     \
    const int kk_ = (kt_);                                                       \
    aH_v = *(const short8*)&aH[abase + (size_t)kk_ * 512];                       \
    aL_v = *(const short8*)&aL[abase + (size_t)kk_ * 512];                       \
    _Pragma("unroll")                                                            \
    for (int nt_ = 0; nt_ < 4; ++nt_) {                                          \
        const size_t bo_ = ((size_t)(nt0 + nt_) * KT + kk_) * 512 + l * 8;       \
        bH_v[nt_] = *(const short8*)&bH[bo_];                                    \
        bL_v[nt_] = *(const short8*)&bL[bo_];                                    \
    }                                                                            \
} while (0)

#define GC(aH_v, aL_v, bH_v, bL_v) do {                                          \
    _Pragma("unroll")                                                            \
    for (int nt_ = 0; nt_ < 4; ++nt_) {                                          \
        acc[nt_] = __builtin_amdgcn_mfma_f32_16x16x32_bf16(aH_v, bH_v[nt_], acc[nt_], 0, 0, 0); \
        acc[nt_] = __builtin_amdgcn_mfma_f32_16x16x32_bf16(aH_v, bL_v[nt_], acc[nt_], 0, 0, 0); \
        acc[nt_] = __builtin_amdgcn_mfma_f32_16x16x32_bf16(aL_v, bH_v[nt_], acc[nt_], 0, 0, 0); \
    }                                                                            \
} while (0)

    short8 aHa, aLa, bHa[4], bLa[4], aHb, aLb, bHb[4], bLb[4];
    GL(aHa, aLa, bHa, bLa, 0);
    GL(aHb, aLb, bHb, bLb, 1);
    for (int kt = 0; kt < KT; kt += 2) {
        GC(aHa, aLa, bHa, bLa);
        if (kt + 2 < KT) GL(aHa, aLa, bHa, bLa, kt + 2);
        GC(aHb, aLb, bHb, bLb);
        if (kt + 3 < KT) GL(aHb, aLb, bHb, bLb, kt + 3);
    }
#undef GL
#undef GC

    // (1) bf16 PV fragments direct from acc
    #pragma unroll
    for (int nt = 0; nt < 4; ++nt) {
        s16x4 u;
        #pragma unroll
        for (int c = 0; c < 4; ++c) u[c] = (short)f2bfu(acc[nt][c]);
        const int f = (mt >> 1) * NT + (nt0 + nt);
        *(s16x4*)&gpO[(size_t)f * 512 + l * 8 + 4 * (mt & 1)] = u;
    }
    // (2) scores via 16-lane reduce + atomicAdd
    const float* al = av;
    const float* ar = av + dh;
    float pl[4] = {0.f, 0.f, 0.f, 0.f}, pr[4] = {0.f, 0.f, 0.f, 0.f};
    #pragma unroll
    for (int nt = 0; nt < 4; ++nt) {
        const int q = (cb * 64 + 16 * nt + n16) & (dh - 1);
        const float wl = al[q], wr_ = ar[q];
        #pragma unroll
        for (int r = 0; r < 4; ++r) { pl[r] += acc[nt][r] * wl; pr[r] += acc[nt][r] * wr_; }
    }
    #pragma unroll
    for (int r = 0; r < 4; ++r) {
        #pragma unroll
        for (int off = 1; off < 16; off <<= 1) {
            pl[r] += __shfl_xor(pl[r], off);
            pr[r] += __shfl_xor(pr[r], off);
        }
    }
    if (n16 == 0) {
        const int hbase = (dh == 64 ? cb : 0) * NN;
        #pragma unroll
        for (int r = 0; r < 4; ++r) {
            const int grow = 16 * mt + 4 * gq + r;
            atomicAdd(&slO[hbase + grow], pl[r] * LOG2E);
            atomicAdd(&srO[hbase + grow], pr[r] * LOG2E);
        }
    }
}

// ---------------- fused masked-softmax attention, MT row-tiles/wave ----------------
// All 8 waves cover the same MT*16 rows; js = w (8-way j-split), NITER = 4 tiles.
// Half-tile ping-pong: buffer = {4 B-frags, 2 sr-vec4, MT u32 masks} per 32-j half.
// OUTMODE 0: fp32 out, MT rounds. OUTMODE 1 (MT=2): split-bf16 A-frags for next GEMM.
template<int MT, int OUTMODE>
__global__ __launch_bounds__(512, 4) void attn_mfma6(
    const float* __restrict__ slv, const float* __restrict__ srv,
    const unsigned short* __restrict__ gp, const unsigned int* __restrict__ adjm32,
    float* __restrict__ out, unsigned short* __restrict__ aoH, unsigned short* __restrict__ aoL,
    int out_cols, int hsel, int do_elu, int ntg_total)
{
    const int t = threadIdx.x, w = t >> 6, l = t & 63;
    const int gq = l >> 4, n16 = l & 15;
    const int i0 = blockIdx.x * (MT * 16);
    const int cb = blockIdx.y;
    const int h = (hsel < 0) ? cb : hsel;
    const int ntg0 = cb * 4;
    const float* srh = srv + (size_t)h * NN;
    int arow[MT];
    float slr[MT];
    #pragma unroll
    for (int mt = 0; mt < MT; ++mt) {
        arow[mt] = i0 + 16 * mt + n16;
        slr[mt] = slv[(size_t)h * NN + arow[mt]];
    }

    __shared__ float accs_raw[8320];   // 33280 B, 65-padded rows
    __shared__ float zp[8][MT * 16];

    f32x4 acc[MT][4];
    float zacc[MT];
    #pragma unroll
    for (int mt = 0; mt < MT; ++mt) {
        zacc[mt] = 0.f;
        #pragma unroll
        for (int nt = 0; nt < 4; ++nt) acc[mt][nt] = f32x4{0.f, 0.f, 0.f, 0.f};
    }

#define LOADH(bf_, sr_, am_, tile_, s_) do {                                     \
    const int tl_ = (tile_);                                                     \
    _Pragma("unroll")                                                            \
    for (int nt_ = 0; nt_ < 4; ++nt_)                                            \
        bf_[nt_] = *(const short8*)&gp[                                          \
            (size_t)((2 * tl_ + (s_)) * ntg_total + ntg0 + nt_) * 512 + l * 8];  \
    _Pragma("unroll")                                                            \
    for (int hb_ = 0; hb_ < 2; ++hb_)                                            \
        sr_[hb_] = *(const f32x4*)&srh[64 * tl_ + 32 * (s_) + 16 * hb_ + 4 * gq];\
    _Pragma("unroll")                                                            \
    for (int mt_ = 0; mt_ < MT; ++mt_)                                           \
        am_[mt_] = adjm32[((size_t)arow[mt_] * 32 + tl_) * 2 + (s_)];            \
} while (0)

#define COMPH(bf_, sr_, am_) do {                                                \
    short8 af_[MT];                                                              \
    _Pragma("unroll")                                                            \
    for (int mt_ = 0; mt_ < MT; ++mt_) {                                         \
        const unsigned am32_ = am_[mt_] >> (4 * gq);                             \
        _Pragma("unroll")                                                        \
        for (int hb_ = 0; hb_ < 2; ++hb_) {                                      \
            const f32x4 s4_ = sr_[hb_];                                          \
            _Pragma("unroll")                                                    \
            for (int c_ = 0; c_ < 4; ++c_) {                                     \
                float f_ = slr[mt_] + s4_[c_];                                   \
                f_ = fmaxf(f_, 0.2f * f_);                                       \
                float wv_ = __builtin_amdgcn_exp2f(f_);                          \
                const int msk_ = (int)(am32_ << (31 - (c_ + 16 * hb_))) >> 31;   \
                wv_ = __int_as_float(__float_as_int(wv_) & msk_);                \
                zacc[mt_] += wv_;                                                \
                af_[mt_][4 * hb_ + c_] = f2bfs(wv_);                             \
            }                                                                    \
        }                                                                        \
    }                                                                            \
    _Pragma("unroll")                                                            \
    for (int mt_ = 0; mt_ < MT; ++mt_)                                           \
        _Pragma("unroll")                                                        \
        for (int nt_ = 0; nt_ < 4; ++nt_)                                        \
            acc[mt_][nt_] = __builtin_amdgcn_mfma_f32_16x16x32_bf16(             \
                af_[mt_], bf_[nt_], acc[mt_][nt_], 0, 0, 0);                     \
} while (0)

    unsigned amA[MT], amB[MT];
    f32x4 srA[2], srB[2];
    short8 bfA[4], bfB[4];

    LOADH(bfA, srA, amA, w, 0);
    LOADH(bfB, srB, amB, w, 1);
    #pragma unroll
    for (int k = 0; k < 4; ++k) {
        const int tn = (k < 3) ? (w + 8 * (k + 1)) : (w + 8 * k);   // guarded prefetch
        COMPH(bfA, srA, amA);
        LOADH(bfA, srA, amA, tn, 0);
        COMPH(bfB, srB, amB);
        LOADH(bfB, srB, amB, tn, 1);
    }
#undef LOADH
#undef COMPH

    // ---- Z reduce: lanes {l, l^16, l^32, l^48} share a row ----
    #pragma unroll
    for (int mt = 0; mt < MT; ++mt) {
        zacc[mt] += __shfl_xor(zacc[mt], 16);
        zacc[mt] += __shfl_xor(zacc[mt], 32);
    }
    if (l < 16) {
        #pragma unroll
        for (int mt = 0; mt < MT; ++mt) zp[w][16 * mt + l] = zacc[mt];
    }

    if constexpr (OUTMODE == 0) {
        // MT rounds; each stages one m-subtile, 8 waves write 16 (nt,r) pairs
        #pragma unroll
        for (int msel = 0; msel < MT; ++msel) {
            #pragma unroll
            for (int nt = 0; nt < 4; ++nt)
                #pragma unroll
                for (int r = 0; r < 4; ++r)
                    accs_raw[((w * 4 + nt) * 4 + r) * 65 + l] = acc[msel][nt][r];
            __syncthreads();
            #pragma unroll
            for (int idx = 0; idx < 2; ++idx) {
                const int flat = w + 8 * idx;            // 0..15
                const int nt = flat >> 2, r = flat & 3;
                const int ro = 4 * gq + r;
                float z = 0.f, v = 0.f;
                #pragma unroll
                for (int jj = 0; jj < 8; ++jj) {
                    z += zp[jj][16 * msel + ro];
                    v += accs_raw[((jj * 4 + nt) * 4 + r) * 65 + l];
                }
                float o = v / z;
                if (do_elu) o = (o > 0.f) ? o : (__builtin_amdgcn_exp2f(o * LOG2E) - 1.f);
                out[(size_t)(i0 + 16 * msel + ro) * out_cols + cb * 64 + nt * 16 + n16] = o;
            }
            __syncthreads();
        }
    } else {
        // MT == 2: two rounds (one per ktl); emit split-bf16 A-frags (ELU applied)
        const int mtl = w & 1, eh = (w >> 1) & 1;
        const int rowl = l & 15, colq = l >> 4;
        #pragma unroll
        for (int h2 = 0; h2 < 2; ++h2) {
            #pragma unroll
            for (int mt = 0; mt < MT; ++mt)
                #pragma unroll
                for (int ntl = 0; ntl < 2; ++ntl)
                    #pragma unroll
                    for (int r = 0; r < 4; ++r)
                        accs_raw[(((w * 2 + mt) * 2 + ntl) * 4 + r) * 65 + l] =
                            acc[mt][2 * h2 + ntl][r];
            __syncthreads();
            if (w < 4) {
                const int grow = 16 * mtl + rowl;
                float z = 0.f;
                #pragma unroll
                for (int jj = 0; jj < 8; ++jj) z += zp[jj][grow];
                const float rz = 1.0f / z;
                unsigned short uh[4], ul[4];
                #pragma unroll
                for (int c = 0; c < 4; ++c) {
                    const int c16 = 4 * colq + c;
                    float v = 0.f;
                    #pragma unroll
                    for (int jj = 0; jj < 8; ++jj)
                        v += accs_raw[(((jj * 2 + mtl) * 2 + eh) * 4 + (rowl & 3)) * 65
                                      + (rowl >> 2) * 16 + c16];
                    float o = v * rz;
                    o = (o > 0.f) ? o : (__builtin_amdgcn_exp2f(o * LOG2E) - 1.f);  // ELU
                    const unsigned short hi = f2bfu(o);
                    uh[c] = hi;
                    ul[c] = f2bfu(o - bfu2f(hi));
                }
                const int mtg = blockIdx.x * 2 + mtl;
                const int kt = 2 * cb + h2;
                const size_t off = ((size_t)mtg * 16 + kt) * 512 + l * 8 + 4 * eh;
                *(s16x4*)&aoH[off] = *(const s16x4*)uh;
                *(s16x4*)&aoL[off] = *(const s16x4*)ul;
            }
            __syncthreads();
        }
    }
}

extern "C" void kernel_launch(void* const* d_in, const int* in_sizes, int n_in,
                              void* d_out, int out_size, void* d_ws, size_t ws_size,
                              hipStream_t stream)
{
    const float* x   = (const float*)d_in[0];   // 2048 x 512
    const int*   adj = (const int*)  d_in[1];   // 2048 x 2048
    const float* W1  = (const float*)d_in[2];   // 512 x 512
    const float* a1  = (const float*)d_in[3];   // 128
    const float* W2  = (const float*)d_in[4];   // 512 x 256
    const float* a2  = (const float*)d_in[5];   // 512
    float* out = (float*)d_out;                 // 2048 x 256

    // ---- workspace layout (scores first: zeroed by prep, 36864 floats) ----
    float* sl1 = (float*)d_ws;                  // 8*2048
    float* sr1 = sl1 + 8 * 2048;
    float* sl2 = sr1 + 8 * 2048;                // 2048
    float* sr2 = sl2 + 2048;
    unsigned long long* adjm = (unsigned long long*)(sr2 + 2048);   // 65536 u64
    unsigned short* gp1 = (unsigned short*)(adjm + 65536);          // 2048 frags * 512
    unsigned short* gp2 = gp1 + 2048 * 512;     // 1024 frags
    unsigned short* axH = gp2 + 1024 * 512;     // x A-frags: 2048 frags
    unsigned short* axL = axH + 2048 * 512;
    unsigned short* ahH = axL + 2048 * 512;     // hb A-frags: 2048 frags
    unsigned short* ahL = ahH + 2048 * 512;
    unsigned short* w1H = ahL + 2048 * 512;     // W1 B-frags: 512 frags
    unsigned short* w1L = w1H + 512 * 512;
    unsigned short* w2H = w1L + 512 * 512;      // W2 B-frags: 256 frags
    unsigned short* w2L = w2H + 256 * 512;

    prep<<<dim3(16384), 256, 0, stream>>>(adj, adjm, sl1,
                                          W1, w1H, w1L, W2, w2H, w2L, x, axH, axL);

    // ---- layer 1 ----
    gemm_fused<<<dim3(32, 8), 256, 0, stream>>>(axH, axL, w1H, w1L, a1, gp1, sl1, sr1, 16, 64, 32);
    attn_mfma6<2, 1><<<dim3(64, 8), 512, 0, stream>>>(sl1, sr1, gp1, (const unsigned int*)adjm,
                                                      nullptr, ahH, ahL, 512, -1, 1, 32);

    // ---- layer 2 ----
    gemm_fused<<<dim3(32, 4), 256, 0, stream>>>(ahH, ahL, w2H, w2L, a2, gp2, sl2, sr2, 16, 256, 16);
    // attn2 at MT=2: half the blocks, half the gp2 L2 re-read traffic
    attn_mfma6<2, 0><<<dim3(64, 4), 512, 0, stream>>>(sl2, sr2, gp2, (const unsigned int*)adjm,
                                                      out, nullptr, nullptr, 256, 0, 0, 16);
}

// Round 16
// 54.481 us; speedup vs baseline: 1.3238x; 1.0070x over previous
//
#include <hip/hip_runtime.h>
#include <hip/hip_bf16.h>
#include <math.h>

#define NN 2048
#define LOG2E 1.4426950408889634f

typedef __attribute__((ext_vector_type(8))) short short8;
typedef __attribute__((ext_vector_type(4))) short s16x4;
typedef __attribute__((ext_vector_type(4))) float f32x4;

__device__ inline unsigned short f2bfu(float f) {
    __hip_bfloat16 h = __float2bfloat16(f);
    return *reinterpret_cast<const unsigned short*>(&h);
}
__device__ inline short f2bfs(float f) {
    __hip_bfloat16 h = __float2bfloat16(f);
    return *reinterpret_cast<const short*>(&h);
}
__device__ inline float bfu2f(unsigned short u) {
    return __uint_as_float(((unsigned int)u) << 16);
}

// ---------------- fused prep: adj masks + score-zero + W packs + x A-frags --------
__global__ __launch_bounds__(256) void prep(
    const int* __restrict__ adj, unsigned long long* __restrict__ adjm,
    float* __restrict__ zeros,
    const float* __restrict__ W1, unsigned short* __restrict__ w1H, unsigned short* __restrict__ w1L,
    const float* __restrict__ W2, unsigned short* __restrict__ w2H, unsigned short* __restrict__ w2L,
    const float* __restrict__ x, unsigned short* __restrict__ axH, unsigned short* __restrict__ axL)
{
    const int b = blockIdx.x, t = threadIdx.x, w = t >> 6, l = t & 63;
    const int gq = l >> 4, n16 = l & 15;
    // --- adjacency -> per-row 64-bit masks (all 16384 blocks) ---
    {
        const int gw = b * 4 + w;
        const int row = gw >> 5, ch = gw & 31;
        const int v = adj[(size_t)row * NN + ch * 64 + l];
        const unsigned long long bm = __ballot(v != 0);
        if (l == 0) adjm[gw] = bm;
    }
    if (b < 144) {
        zeros[b * 256 + t] = 0.f;           // sl1,sr1,sl2,sr2 (36864 floats)
    } else if (b >= 256 && b < 448) {
        // --- W1/W2 -> split-bf16 B-frags ---
        int f = (b - 256) * 4 + w;          // 0..767
        const float* B; unsigned short *bH, *bL; int N;
        if (f < 512) { B = W1; bH = w1H; bL = w1L; N = 512; }
        else         { B = W2; bH = w2H; bL = w2L; N = 256; f -= 512; }
        const int nt = f >> 4, kt = f & 15;
        const int col = nt * 16 + n16;
        unsigned short uh[8], ul[8];
        #pragma unroll
        for (int e = 0; e < 8; ++e) {
            const int k = kt * 32 + 4 * gq + (e & 3) + 16 * (e >> 2);
            const float v = B[(size_t)k * N + col];
            const unsigned short hi = f2bfu(v);
            uh[e] = hi;
            ul[e] = f2bfu(v - bfu2f(hi));
        }
        *(short8*)&bH[(size_t)f * 512 + l * 8] = *(const short8*)uh;
        *(short8*)&bL[(size_t)f * 512 + l * 8] = *(const short8*)ul;
    } else if (b >= 448 && b < 960) {
        // --- x -> split-bf16 A-frags (K=512, KT=16) ---
        const int f = (b - 448) * 4 + w;    // 0..2047
        const int mt = f >> 4, kt = f & 15;
        const int row = mt * 16 + n16;
        const int k0 = kt * 32 + 4 * gq;
        unsigned short uh[8], ul[8];
        #pragma unroll
        for (int eh = 0; eh < 2; ++eh) {
            const float4 v4 = *(const float4*)&x[(size_t)row * 512 + k0 + 16 * eh];
            const float vv[4] = {v4.x, v4.y, v4.z, v4.w};
            #pragma unroll
            for (int c = 0; c < 4; ++c) {
                const float v = vv[c];
                const unsigned short hi = f2bfu(v);
                uh[4 * eh + c] = hi;
                ul[4 * eh + c] = f2bfu(v - bfu2f(hi));
            }
        }
        *(short8*)&axH[(size_t)f * 512 + l * 8] = *(const short8*)uh;
        *(short8*)&axL[(size_t)f * 512 + l * 8] = *(const short8*)ul;
    }
}

// ---------------- split-bf16 MFMA GEMM, fused epilogue -----------------------------
// NTW = n-frags per wave (16 cols each). Grid: (M/64, NT/NTW). Wave tile 16 x 16*NTW.
// Smaller NTW => more waves => higher occupancy on this latency-bound kernel.
template<int NTW>
__global__ __launch_bounds__(256, 2) void gemm_fused(
    const unsigned short* __restrict__ aH, const unsigned short* __restrict__ aL,
    const unsigned short* __restrict__ bH, const unsigned short* __restrict__ bL,
    const float* __restrict__ av, unsigned short* __restrict__ gpO,
    float* __restrict__ slO, float* __restrict__ srO,
    int KT, int dh, int NT)
{
    const int t = threadIdx.x, w = t >> 6, l = t & 63;
    const int gq = l >> 4, n16 = l & 15;
    const int mt = blockIdx.x * 4 + w;
    const int nt0 = blockIdx.y * NTW;
    const size_t abase = (size_t)mt * KT * 512 + l * 8;

    f32x4 acc[NTW];
    #pragma unroll
    for (int nt = 0; nt < NTW; ++nt) acc[nt] = f32x4{0.f, 0.f, 0.f, 0.f};

#define GL(aH_v, aL_v, bH_v, bL_v, kt_) do {                                     \
    const int kk_ = (kt_);                                                       \
    aH_v = *(const short8*)&aH[abase + (size_t)kk_ * 512];                       \
    aL_v = *(const short8*)&aL[abase + (size_t)kk_ * 512];                       \
    _Pragma("unroll")                                                            \
    for (int nt_ = 0; nt_ < NTW; ++nt_) {                                        \
        const size_t bo_ = ((size_t)(nt0 + nt_) * KT + kk_) * 512 + l * 8;       \
        bH_v[nt_] = *(const short8*)&bH[bo_];                                    \
        bL_v[nt_] = *(const short8*)&bL[bo_];                                    \
    }                                                                            \
} while (0)

#define GC(aH_v, aL_v, bH_v, bL_v) do {                                          \
    _Pragma("unroll")                                                            \
    for (int nt_ = 0; nt_ < NTW; ++nt_) {                                        \
        acc[nt_] = __builtin_amdgcn_mfma_f32_16x16x32_bf16(aH_v, bH_v[nt_], acc[nt_], 0, 0, 0); \
        acc[nt_] = __builtin_amdgcn_mfma_f32_16x16x32_bf16(aH_v, bL_v[nt_], acc[nt_], 0, 0, 0); \
        acc[nt_] = __builtin_amdgcn_mfma_f32_16x16x32_bf16(aL_v, bH_v[nt_], acc[nt_], 0, 0, 0); \
    }                                                                            \
} while (0)

    short8 aHa, aLa, bHa[NTW], bLa[NTW], aHb, aLb, bHb[NTW], bLb[NTW];
    GL(aHa, aLa, bHa, bLa, 0);
    GL(aHb, aLb, bHb, bLb, 1);
    for (int kt = 0; kt < KT; kt += 2) {
        GC(aHa, aLa, bHa, bLa);
        if (kt + 2 < KT) GL(aHa, aLa, bHa, bLa, kt + 2);
        GC(aHb, aLb, bHb, bLb);
        if (kt + 3 < KT) GL(aHb, aLb, bHb, bLb, kt + 3);
    }
#undef GL
#undef GC

    // (1) bf16 PV fragments direct from acc
    #pragma unroll
    for (int nt = 0; nt < NTW; ++nt) {
        s16x4 u;
        #pragma unroll
        for (int c = 0; c < 4; ++c) u[c] = (short)f2bfu(acc[nt][c]);
        const int f = (mt >> 1) * NT + (nt0 + nt);
        *(s16x4*)&gpO[(size_t)f * 512 + l * 8 + 4 * (mt & 1)] = u;
    }
    // (2) scores via 16-lane reduce + atomicAdd (sub-head partials merge atomically)
    const float* al = av;
    const float* ar = av + dh;
    float pl[4] = {0.f, 0.f, 0.f, 0.f}, pr[4] = {0.f, 0.f, 0.f, 0.f};
    #pragma unroll
    for (int nt = 0; nt < NTW; ++nt) {
        const int gcol = (nt0 + nt) * 16 + n16;
        const int q = gcol & (dh - 1);
        const float wl = al[q], wr_ = ar[q];
        #pragma unroll
        for (int r = 0; r < 4; ++r) { pl[r] += acc[nt][r] * wl; pr[r] += acc[nt][r] * wr_; }
    }
    #pragma unroll
    for (int r = 0; r < 4; ++r) {
        #pragma unroll
        for (int off = 1; off < 16; off <<= 1) {
            pl[r] += __shfl_xor(pl[r], off);
            pr[r] += __shfl_xor(pr[r], off);
        }
    }
    if (n16 == 0) {
        const int hbase = (dh == 64) ? ((nt0 * 16) >> 6) * NN : 0;
        #pragma unroll
        for (int r = 0; r < 4; ++r) {
            const int grow = 16 * mt + 4 * gq + r;
            atomicAdd(&slO[hbase + grow], pl[r] * LOG2E);
            atomicAdd(&srO[hbase + grow], pr[r] * LOG2E);
        }
    }
}

// ---------------- fused masked-softmax attention, MT row-tiles/wave ----------------
// All 8 waves cover the same MT*16 rows; js = w (8-way j-split), NITER = 4 tiles.
// Half-tile ping-pong: buffer = {4 B-frags, 2 sr-vec4, MT u32 masks} per 32-j half.
// OUTMODE 0: fp32 out, MT rounds. OUTMODE 1 (MT=2): split-bf16 A-frags for next GEMM.
template<int MT, int OUTMODE>
__global__ __launch_bounds__(512, 4) void attn_mfma6(
    const float* __restrict__ slv, const float* __restrict__ srv,
    const unsigned short* __restrict__ gp, const unsigned int* __restrict__ adjm32,
    float* __restrict__ out, unsigned short* __restrict__ aoH, unsigned short* __restrict__ aoL,
    int out_cols, int hsel, int do_elu, int ntg_total)
{
    const int t = threadIdx.x, w = t >> 6, l = t & 63;
    const int gq = l >> 4, n16 = l & 15;
    const int i0 = blockIdx.x * (MT * 16);
    const int cb = blockIdx.y;
    const int h = (hsel < 0) ? cb : hsel;
    const int ntg0 = cb * 4;
    const float* srh = srv + (size_t)h * NN;
    int arow[MT];
    float slr[MT];
    #pragma unroll
    for (int mt = 0; mt < MT; ++mt) {
        arow[mt] = i0 + 16 * mt + n16;
        slr[mt] = slv[(size_t)h * NN + arow[mt]];
    }

    __shared__ float accs_raw[8320];   // 33280 B, 65-padded rows
    __shared__ float zp[8][MT * 16];

    f32x4 acc[MT][4];
    float zacc[MT];
    #pragma unroll
    for (int mt = 0; mt < MT; ++mt) {
        zacc[mt] = 0.f;
        #pragma unroll
        for (int nt = 0; nt < 4; ++nt) acc[mt][nt] = f32x4{0.f, 0.f, 0.f, 0.f};
    }

#define LOADH(bf_, sr_, am_, tile_, s_) do {                                     \
    const int tl_ = (tile_);                                                     \
    _Pragma("unroll")                                                            \
    for (int nt_ = 0; nt_ < 4; ++nt_)                                            \
        bf_[nt_] = *(const short8*)&gp[                                          \
            (size_t)((2 * tl_ + (s_)) * ntg_total + ntg0 + nt_) * 512 + l * 8];  \
    _Pragma("unroll")                                                            \
    for (int hb_ = 0; hb_ < 2; ++hb_)                                            \
        sr_[hb_] = *(const f32x4*)&srh[64 * tl_ + 32 * (s_) + 16 * hb_ + 4 * gq];\
    _Pragma("unroll")                                                            \
    for (int mt_ = 0; mt_ < MT; ++mt_)                                           \
        am_[mt_] = adjm32[((size_t)arow[mt_] * 32 + tl_) * 2 + (s_)];            \
} while (0)

#define COMPH(bf_, sr_, am_) do {                                                \
    short8 af_[MT];                                                              \
    _Pragma("unroll")                                                            \
    for (int mt_ = 0; mt_ < MT; ++mt_) {                                         \
        const unsigned am32_ = am_[mt_] >> (4 * gq);                             \
        _Pragma("unroll")                                                        \
        for (int hb_ = 0; hb_ < 2; ++hb_) {                                      \
            const f32x4 s4_ = sr_[hb_];                                          \
            _Pragma("unroll")                                                    \
            for (int c_ = 0; c_ < 4; ++c_) {                                     \
                float f_ = slr[mt_] + s4_[c_];                                   \
                f_ = fmaxf(f_, 0.2f * f_);                                       \
                float wv_ = __builtin_amdgcn_exp2f(f_);                          \
                const int msk_ = (int)(am32_ << (31 - (c_ + 16 * hb_))) >> 31;   \
                wv_ = __int_as_float(__float_as_int(wv_) & msk_);                \
                zacc[mt_] += wv_;                                                \
                af_[mt_][4 * hb_ + c_] = f2bfs(wv_);                             \
            }                                                                    \
        }                                                                        \
    }                                                                            \
    _Pragma("unroll")                                                            \
    for (int mt_ = 0; mt_ < MT; ++mt_)                                           \
        _Pragma("unroll")                                                        \
        for (int nt_ = 0; nt_ < 4; ++nt_)                                        \
            acc[mt_][nt_] = __builtin_amdgcn_mfma_f32_16x16x32_bf16(             \
                af_[mt_], bf_[nt_], acc[mt_][nt_], 0, 0, 0);                     \
} while (0)

    unsigned amA[MT], amB[MT];
    f32x4 srA[2], srB[2];
    short8 bfA[4], bfB[4];

    LOADH(bfA, srA, amA, w, 0);
    LOADH(bfB, srB, amB, w, 1);
    #pragma unroll
    for (int k = 0; k < 4; ++k) {
        const int tn = (k < 3) ? (w + 8 * (k + 1)) : (w + 8 * k);   // guarded prefetch
        COMPH(bfA, srA, amA);
        LOADH(bfA, srA, amA, tn, 0);
        COMPH(bfB, srB, amB);
        LOADH(bfB, srB, amB, tn, 1);
    }
#undef LOADH
#undef COMPH

    // ---- Z reduce: lanes {l, l^16, l^32, l^48} share a row ----
    #pragma unroll
    for (int mt = 0; mt < MT; ++mt) {
        zacc[mt] += __shfl_xor(zacc[mt], 16);
        zacc[mt] += __shfl_xor(zacc[mt], 32);
    }
    if (l < 16) {
        #pragma unroll
        for (int mt = 0; mt < MT; ++mt) zp[w][16 * mt + l] = zacc[mt];
    }

    if constexpr (OUTMODE == 0) {
        // MT rounds; each stages one m-subtile, 8 waves write 16 (nt,r) pairs
        #pragma unroll
        for (int msel = 0; msel < MT; ++msel) {
            #pragma unroll
            for (int nt = 0; nt < 4; ++nt)
                #pragma unroll
                for (int r = 0; r < 4; ++r)
                    accs_raw[((w * 4 + nt) * 4 + r) * 65 + l] = acc[msel][nt][r];
            __syncthreads();
            #pragma unroll
            for (int idx = 0; idx < 2; ++idx) {
                const int flat = w + 8 * idx;            // 0..15
                const int nt = flat >> 2, r = flat & 3;
                const int ro = 4 * gq + r;
                float z = 0.f, v = 0.f;
                #pragma unroll
                for (int jj = 0; jj < 8; ++jj) {
                    z += zp[jj][16 * msel + ro];
                    v += accs_raw[((jj * 4 + nt) * 4 + r) * 65 + l];
                }
                float o = v / z;
                if (do_elu) o = (o > 0.f) ? o : (__builtin_amdgcn_exp2f(o * LOG2E) - 1.f);
                out[(size_t)(i0 + 16 * msel + ro) * out_cols + cb * 64 + nt * 16 + n16] = o;
            }
            __syncthreads();
        }
    } else {
        // MT == 2: two rounds (one per ktl); emit split-bf16 A-frags (ELU applied)
        const int mtl = w & 1, eh = (w >> 1) & 1;
        const int rowl = l & 15, colq = l >> 4;
        #pragma unroll
        for (int h2 = 0; h2 < 2; ++h2) {
            #pragma unroll
            for (int mt = 0; mt < MT; ++mt)
                #pragma unroll
                for (int ntl = 0; ntl < 2; ++ntl)
                    #pragma unroll
                    for (int r = 0; r < 4; ++r)
                        accs_raw[(((w * 2 + mt) * 2 + ntl) * 4 + r) * 65 + l] =
                            acc[mt][2 * h2 + ntl][r];
            __syncthreads();
            if (w < 4) {
                const int grow = 16 * mtl + rowl;
                float z = 0.f;
                #pragma unroll
                for (int jj = 0; jj < 8; ++jj) z += zp[jj][grow];
                const float rz = 1.0f / z;
                unsigned short uh[4], ul[4];
                #pragma unroll
                for (int c = 0; c < 4; ++c) {
                    const int c16 = 4 * colq + c;
                    float v = 0.f;
                    #pragma unroll
                    for (int jj = 0; jj < 8; ++jj)
                        v += accs_raw[(((jj * 2 + mtl) * 2 + eh) * 4 + (rowl & 3)) * 65
                                      + (rowl >> 2) * 16 + c16];
                    float o = v * rz;
                    o = (o > 0.f) ? o : (__builtin_amdgcn_exp2f(o * LOG2E) - 1.f);  // ELU
                    const unsigned short hi = f2bfu(o);
                    uh[c] = hi;
                    ul[c] = f2bfu(o - bfu2f(hi));
                }
                const int mtg = blockIdx.x * 2 + mtl;
                const int kt = 2 * cb + h2;
                const size_t off = ((size_t)mtg * 16 + kt) * 512 + l * 8 + 4 * eh;
                *(s16x4*)&aoH[off] = *(const s16x4*)uh;
                *(s16x4*)&aoL[off] = *(const s16x4*)ul;
            }
            __syncthreads();
        }
    }
}

extern "C" void kernel_launch(void* const* d_in, const int* in_sizes, int n_in,
                              void* d_out, int out_size, void* d_ws, size_t ws_size,
                              hipStream_t stream)
{
    const float* x   = (const float*)d_in[0];   // 2048 x 512
    const int*   adj = (const int*)  d_in[1];   // 2048 x 2048
    const float* W1  = (const float*)d_in[2];   // 512 x 512
    const float* a1  = (const float*)d_in[3];   // 128
    const float* W2  = (const float*)d_in[4];   // 512 x 256
    const float* a2  = (const float*)d_in[5];   // 512
    float* out = (float*)d_out;                 // 2048 x 256

    // ---- workspace layout (scores first: zeroed by prep, 36864 floats) ----
    float* sl1 = (float*)d_ws;                  // 8*2048
    float* sr1 = sl1 + 8 * 2048;
    float* sl2 = sr1 + 8 * 2048;                // 2048
    float* sr2 = sl2 + 2048;
    unsigned long long* adjm = (unsigned long long*)(sr2 + 2048);   // 65536 u64
    unsigned short* gp1 = (unsigned short*)(adjm + 65536);          // 2048 frags * 512
    unsigned short* gp2 = gp1 + 2048 * 512;     // 1024 frags
    unsigned short* axH = gp2 + 1024 * 512;     // x A-frags: 2048 frags
    unsigned short* axL = axH + 2048 * 512;
    unsigned short* ahH = axL + 2048 * 512;     // hb A-frags: 2048 frags
    unsigned short* ahL = ahH + 2048 * 512;
    unsigned short* w1H = ahL + 2048 * 512;     // W1 B-frags: 512 frags
    unsigned short* w1L = w1H + 512 * 512;
    unsigned short* w2H = w1L + 512 * 512;      // W2 B-frags: 256 frags
    unsigned short* w2L = w2H + 256 * 512;

    prep<<<dim3(16384), 256, 0, stream>>>(adj, adjm, sl1,
                                          W1, w1H, w1L, W2, w2H, w2L, x, axH, axL);

    // ---- layer 1: NTW=2 -> grid (32,16) = 2048 waves = 2 waves/SIMD ----
    gemm_fused<2><<<dim3(32, 16), 256, 0, stream>>>(axH, axL, w1H, w1L, a1, gp1, sl1, sr1, 16, 64, 32);
    attn_mfma6<2, 1><<<dim3(64, 8), 512, 0, stream>>>(sl1, sr1, gp1, (const unsigned int*)adjm,
                                                      nullptr, ahH, ahL, 512, -1, 1, 32);

    // ---- layer 2: NTW=1 -> grid (32,16) = 2048 waves = 2 waves/SIMD ----
    gemm_fused<1><<<dim3(32, 16), 256, 0, stream>>>(ahH, ahL, w2H, w2L, a2, gp2, sl2, sr2, 16, 256, 16);
    // attn2 at MT=2: half the blocks, half the gp2 L2 re-read traffic
    attn_mfma6<2, 0><<<dim3(64, 4), 512, 0, stream>>>(sl2, sr2, gp2, (const unsigned int*)adjm,
                                                      out, nullptr, nullptr, 256, 0, 0, 16);
}